// Round 2
// baseline (403.143 us; speedup 1.0000x reference)
//
#include <hip/hip_runtime.h>
#include <stdint.h>
#include <math.h>

// Problem constants (B=4,S=2048 -> T=8192; H=1024; 2H=2048; E=8; K=2)
#define T_TOK 8192
#define H_DIM 1024
#define H2    2048
#define NE    8

typedef unsigned short u16;
typedef __attribute__((ext_vector_type(8))) short bf16x8;   // 8 bf16 in 4 VGPRs
typedef __attribute__((ext_vector_type(4))) float f32x4;    // MFMA 16x16 C/D

__device__ __forceinline__ u16 f32_to_bf16(float f) {
  union { float f; unsigned u; } c; c.f = f;
  unsigned u = c.u + 0x7fffu + ((c.u >> 16) & 1u);  // RNE
  return (u16)(u >> 16);
}
__device__ __forceinline__ float bf2f(u16 v) {
  union { unsigned u; float f; } c; c.u = (unsigned)v << 16; return c.f;
}

// fast gelu (tanh form), |err| vs exact erf-gelu <= ~1e-3 (absmax 1.56e-2
// vs threshold 4.9e-2, stable across rounds)
__device__ __forceinline__ float fast_gelu(float v) {
  float u = v * v;
  float z2 = v * fmaf(u, 0.1029437f, 2.3022078f);
  float e = __builtin_amdgcn_exp2f(z2);
  float r = __builtin_amdgcn_rcpf(1.0f + e);
  return v - v * r;
}

// async global->LDS, 16B per lane. LDS dest is wave-uniform base + lane*16;
// global address is per-lane (exploited for the XOR bank swizzle).
__device__ __forceinline__ void g2l16(const void* g, void* l) {
  __builtin_amdgcn_global_load_lds(
      (const __attribute__((address_space(1))) unsigned*)g,
      (__attribute__((address_space(3))) unsigned*)l, 16, 0, 0);
}

// exclusive prefix of 8 counts, computed per-block
__device__ __forceinline__ int prefix_base(const int* counts, int e) {
  int b = 0;
#pragma unroll
  for (int j = 0; j < NE; j++) b += (j < e) ? counts[j] : 0;
  return b;
}

// ---------------- Prep: router (blocks 0..2047) + w1/w2 cvt (rest).
__global__ __launch_bounds__(256) void prep_kernel(
    const float* __restrict__ x, const float* __restrict__ rw,
    const float* __restrict__ w1, const float* __restrict__ w2,
    u16* __restrict__ xb, u16* __restrict__ w1b, u16* __restrict__ w2b,
    int* __restrict__ tope, float2* __restrict__ gate2,
    int* __restrict__ counts) {
  int blk = blockIdx.x;
  if (blk < T_TOK / 4) {
    int wave = threadIdx.x >> 6;
    int lane = threadIdx.x & 63;
    int t = blk * 4 + wave;
    const float4* x4 = (const float4*)(x + (size_t)t * H_DIM);
    const float4* rw4 = (const float4*)rw;
    u16* xbrow = xb + (size_t)t * H_DIM;

    double acc[NE];
#pragma unroll
    for (int e = 0; e < NE; e++) acc[e] = 0.0;
#pragma unroll
    for (int i = 0; i < 4; i++) {
      int c = lane + 64 * i;
      float4 xv = x4[c];
      ushort4 bv = make_ushort4(f32_to_bf16(xv.x), f32_to_bf16(xv.y),
                                f32_to_bf16(xv.z), f32_to_bf16(xv.w));
      *(ushort4*)(xbrow + c * 4) = bv;
#pragma unroll
      for (int e = 0; e < NE; e++) {
        float4 wv = rw4[e * 256 + c];
        acc[e] += (double)xv.x * wv.x + (double)xv.y * wv.y +
                  (double)xv.z * wv.z + (double)xv.w * wv.w;
      }
    }
#pragma unroll
    for (int off = 32; off >= 1; off >>= 1)
#pragma unroll
      for (int e = 0; e < NE; e++) acc[e] += __shfl_xor(acc[e], off, 64);

    if (lane == 0) {
      int e0 = 0; double v0 = acc[0];
#pragma unroll
      for (int e = 1; e < NE; e++) if (acc[e] > v0) { v0 = acc[e]; e0 = e; }
      int e1 = -1; double v1 = -1e300;
#pragma unroll
      for (int e = 0; e < NE; e++) if (e != e0 && acc[e] > v1) { v1 = acc[e]; e1 = e; }
      double ex = exp(v1 - v0);
      tope[t] = e0 | (e1 << 8);
      gate2[t] = make_float2((float)(1.0 / (1.0 + ex)), (float)(ex / (1.0 + ex)));
    }
  } else {
    int cb = blk - T_TOK / 4;
    if (cb == 0 && threadIdx.x < NE) counts[threadIdx.x] = 0;
    const float* src; u16* dst;
    if (cb < 3072) { src = w1; dst = w1b; }
    else           { src = w2; dst = w2b; cb -= 3072; }
    const int n4 = NE * H2 * H_DIM / 4;
    const int stride = 3072 * 256;
    const float4* s4 = (const float4*)src;
    for (int i = cb * 256 + threadIdx.x; i < n4; i += stride) {
      float4 v = s4[i];
      *(ushort4*)(dst + (size_t)i * 4) = make_ushort4(
          f32_to_bf16(v.x), f32_to_bf16(v.y), f32_to_bf16(v.z), f32_to_bf16(v.w));
    }
  }
}

// ---------------- Build expert lists: counting sort over 8 bins.
__global__ __launch_bounds__(256) void build_kernel(
    const int* __restrict__ tope, int* __restrict__ counts,
    int* __restrict__ tok_list, int2* __restrict__ pos2) {
  __shared__ int cts[4][NE];
  __shared__ int gbase[NE];
  int tid = threadIdx.x, lane = tid & 63, w = tid >> 6;
  int t = blockIdx.x * 256 + tid;
  int pk = tope[t];
  int e0 = pk & 0xff, e1 = (pk >> 8) & 0xff;
  unsigned long long lt = ((unsigned long long)1 << lane) - 1;

  int r0 = 0, r1 = 0;
#pragma unroll
  for (int e = 0; e < NE; e++) {
    unsigned long long b0 = __ballot(e0 == e);
    unsigned long long b1 = __ballot(e1 == e);
    int n0 = __popcll(b0), n1 = __popcll(b1);
    if (e0 == e) r0 = __popcll(b0 & lt);
    if (e1 == e) r1 = n0 + __popcll(b1 & lt);
    if (lane == 0) cts[w][e] = n0 + n1;
  }
  __syncthreads();
  if (tid < NE) {
    int bt = cts[0][tid] + cts[1][tid] + cts[2][tid] + cts[3][tid];
    gbase[tid] = atomicAdd(&counts[tid], bt);
  }
  __syncthreads();
  int off0 = gbase[e0] + r0;
  int off1 = gbase[e1] + r1;
#pragma unroll
  for (int wp = 0; wp < 4; wp++) {
    if (wp < w) { off0 += cts[wp][e0]; off1 += cts[wp][e1]; }
  }
  tok_list[e0 * T_TOK + off0] = t;
  tok_list[e1 * T_TOK + off1] = t;
  pos2[t] = make_int2(off0, off1);
}

// ---------------- Grouped GEMM: m201-style 8-phase schedule.
// 256x256 tile, BK=64, 8 waves (2M x 4N, each 128x64 out), LDS 128 KiB =
// [2 tensors][2 dbuf][2 halves][128 rows][64 cols] bf16.
//
// Halves are grouped by PHASE USAGE (not row order):
//   A-half h = rows with ((row>>6)&1)==h  (frags 0-3 vs 4-7 of both wave-rows)
//   B-half h = rows with ((row>>5)&1)==h  (n-frags 0-1 vs 2-3 of all 4 waves)
// so each half's last LDS read is in exactly one phase -> half-granular
// same-dbuf staging is WAR-safe.
//
// Per tile t (dbuf d=t&1), 4 phases = C-quadrants; each phase:
//   {ds_reads | stage 1 half | s_barrier | 16 MFMA (setprio) | s_barrier}
//   P1 (m0n0): read A0(8)+B0(4); stage A1(t+1)->~d
//   P2 (m0n1): read B1(4);       stage A0(t+2)->d   (A0[d] last read P1)
//   P3 (m1n0): read A1(8);       stage B0(t+2)->d   (B0[d] last read P1)
//   P4 (m1n1): no reads;         stage B1(t+2)->d   (B1[d] last read P2)
//   vmcnt(6) once per tile at P4: leaves exactly {A0,B0,B1}(t+2) = 3
//   half-tiles (6 loads) in flight across every tile boundary; every half
//   retires >=1 barrier before its first read. Tail peels 2 tiles.
//
// XOR swizzle for 64B rows: phys_slot = logical_slot ^ (lr&7); staged via
// pre-swizzled GLOBAL chunk, LDS dest linear (both-sides-or-neither).
#define SB  __builtin_amdgcn_sched_barrier(0)
#define BAR() do { SB; __builtin_amdgcn_s_barrier(); SB; } while (0)
#define VMW(N) asm volatile("s_waitcnt vmcnt(" #N ")" ::: "memory")

#define LDA(D,H,F,KK) (*(const bf16x8*)&lA[(((D)*2+(H))<<13) + adA[F][KK]])
#define LDB(D,H,J,KK) (*(const bf16x8*)&lB[(((D)*2+(H))<<13) + adB[J][KK]])

#define RDA(D,H) do { _Pragma("unroll") \
  for (int f_ = 0; f_ < 4; ++f_) { af[f_][0] = LDA(D,H,f_,0); af[f_][1] = LDA(D,H,f_,1); } } while (0)
#define RDB(D,H,BP) do { \
  BP[0][0]=LDB(D,H,0,0); BP[0][1]=LDB(D,H,0,1); \
  BP[1][0]=LDB(D,H,1,0); BP[1][1]=LDB(D,H,1,1); } while (0)

#define STGA(D,H,KT) do { \
  g2l16(aptr[H][0] + (KT)*64, &lA[(((D)*2+(H))<<13) + sd0]); \
  g2l16(aptr[H][1] + (KT)*64, &lA[(((D)*2+(H))<<13) + sd1]); } while (0)
#define STGB(D,H,KT) do { \
  g2l16(bptr[H][0] + (KT)*64, &lB[(((D)*2+(H))<<13) + sd0]); \
  g2l16(bptr[H][1] + (KT)*64, &lB[(((D)*2+(H))<<13) + sd1]); } while (0)

#define MMQ(FB, BP, NB) do { \
  __builtin_amdgcn_s_setprio(1); \
  _Pragma("unroll") \
  for (int f_ = 0; f_ < 4; ++f_) \
    _Pragma("unroll") \
    for (int j_ = 0; j_ < 2; ++j_) \
      _Pragma("unroll") \
      for (int k_ = 0; k_ < 2; ++k_) \
        acc[(FB)+f_][(NB)+j_] = __builtin_amdgcn_mfma_f32_16x16x32_bf16( \
            af[f_][k_], BP[j_][k_], acc[(FB)+f_][(NB)+j_], 0, 0, 0); \
  __builtin_amdgcn_s_setprio(0); \
} while (0)

#define TILE_FULL(D, KT) do { \
  RDA(D,0); RDB(D,0,b0); SB; STGA(((D)^1), 1, (KT)+1); \
  BAR(); MMQ(0, b0, 0); BAR(); \
  RDB(D,1,b1); SB; STGA(D, 0, (KT)+2); \
  BAR(); MMQ(0, b1, 2); BAR(); \
  RDA(D,1); SB; STGB(D, 0, (KT)+2); \
  BAR(); MMQ(4, b0, 0); BAR(); \
  SB; STGB(D, 1, (KT)+2); \
  BAR(); MMQ(4, b1, 2); VMW(6); BAR(); \
} while (0)

#define TILE_TAIL1(D, KT) do { \
  RDA(D,0); RDB(D,0,b0); SB; STGA(((D)^1), 1, (KT)+1); \
  BAR(); MMQ(0, b0, 0); BAR(); \
  RDB(D,1,b1); BAR(); MMQ(0, b1, 2); BAR(); \
  RDA(D,1); BAR(); MMQ(4, b0, 0); BAR(); \
  MMQ(4, b1, 2); VMW(0); BAR(); \
} while (0)

#define TILE_TAIL0(D) do { \
  RDA(D,0); RDB(D,0,b0); BAR(); MMQ(0, b0, 0); BAR(); \
  RDB(D,1,b1); BAR(); MMQ(0, b1, 2); BAR(); \
  RDA(D,1); BAR(); MMQ(4, b0, 0); BAR(); \
  MMQ(4, b1, 2); \
} while (0)

template <int NKT, int NT, int OUTN, bool GATHER, bool GELU>
__global__ __launch_bounds__(512, 2) void moe_gemm(
    const u16* __restrict__ A, const u16* __restrict__ W,
    u16* __restrict__ O, const int* __restrict__ tok_list,
    const int* __restrict__ counts) {
  const int MTMAX = T_TOK / 256;  // 32
  int e = blockIdx.x / (MTMAX * NT);
  int rem = blockIdx.x % (MTMAX * NT);
  int mt = rem / NT, nt = rem % NT;
  int cnt = counts[e];
  int m0 = mt * 256;
  if (m0 >= cnt) return;
  int base = prefix_base(counts, e);
  const int K = NKT * 64;

  __shared__ u16 lA[32768];   // [dbuf][half][128][64] bf16 = 64 KB
  __shared__ u16 lB[32768];   // 64 KB

  int tid = threadIdx.x;
  int ln = tid & 63, w = tid >> 6;
  int wr = w >> 2, wc = w & 3;             // 2M x 4N wave grid
  int quad = ln >> 4, l16 = ln & 15;

  // ---- staging: thread -> (half-local row lr, swizzled chunk) per call c
  int sd0 = w * 1024 + ln * 8;             // LDS dest (u16) for call 0
  int sd1 = sd0 + 512;                     // call 1
  const u16* We = W + (size_t)e * OUTN * K;
  const u16* aptr[2][2]; const u16* bptr[2][2];
#pragma unroll
  for (int c = 0; c < 2; ++c) {
    int j16 = w * 128 + c * 64 + ln;       // 16B unit within half
    int lr = j16 >> 3;                     // half-local row 0..127
    int chunk = (j16 & 7) ^ (lr & 7);      // pre-swizzled source chunk
#pragma unroll
    for (int h = 0; h < 2; ++h) {
      int arow = ((lr >> 6) << 7) + h * 64 + (lr & 63);
      int ar = m0 + arow; if (ar > cnt - 1) ar = cnt - 1;
      const u16* ab;
      if (GATHER) ab = A + (size_t)tok_list[e * T_TOK + ar] * K;
      else        ab = A + (size_t)(base + ar) * K;
      aptr[h][c] = ab + chunk * 8;
      int brow = ((lr >> 5) << 6) + h * 32 + (lr & 31);
      bptr[h][c] = We + (size_t)(nt * 256 + brow) * K + chunk * 8;
    }
  }

  // ---- read addresses (u16, within a 8192-u16 half segment)
  int adA[4][2], adB[2][2];
#pragma unroll
  for (int f = 0; f < 4; ++f) {
    int lr = wr * 64 + f * 16 + l16;
#pragma unroll
    for (int kk = 0; kk < 2; ++kk)
      adA[f][kk] = lr * 64 + ((((kk << 2) | quad) ^ (lr & 7)) << 3);
  }
#pragma unroll
  for (int j = 0; j < 2; ++j) {
    int lr = wc * 32 + j * 16 + l16;
#pragma unroll
    for (int kk = 0; kk < 2; ++kk)
      adB[j][kk] = lr * 64 + ((((kk << 2) | quad) ^ (lr & 7)) << 3);
  }

  f32x4 acc[8][4];
#pragma unroll
  for (int i = 0; i < 8; i++)
#pragma unroll
    for (int j = 0; j < 4; j++)
#pragma unroll
      for (int r = 0; r < 4; r++) acc[i][j][r] = 0.f;

  bf16x8 af[4][2], b0[2][2], b1[2][2];

  // ---- prologue: 7 halves in stream order; vmcnt(6) retires all of tile 0,
  // leaves {A0,B0,B1}(1) = 6 loads in flight (steady state).
  STGA(0,0,0); STGB(0,0,0); STGB(0,1,0); STGA(0,1,0);
  STGA(1,0,1); STGB(1,0,1); STGB(1,1,1);
  VMW(6);
  BAR();

#pragma unroll 1
  for (int t = 0; t < NKT - 2; t += 2) {
    TILE_FULL(0, t);
    TILE_FULL(1, t + 1);
  }
  TILE_TAIL1(0, NKT - 2);   // NKT even -> d=0
  TILE_TAIL0(1);

  // epilogue: C/D layout col=lane&15, row=quad*4+reg
#pragma unroll
  for (int mi = 0; mi < 8; ++mi) {
    int rb = wr * 128 + mi * 16 + quad * 4;
#pragma unroll
    for (int r = 0; r < 4; ++r) {
      int grow = m0 + rb + r;
      if (grow < cnt) {
        size_t o = (size_t)(base + grow) * OUTN + nt * 256 + wc * 64 + l16;
#pragma unroll
        for (int ni = 0; ni < 4; ++ni) {
          float v = acc[mi][ni][r];
          if (GELU) v = fast_gelu(v);
          O[o + ni * 16] = f32_to_bf16(v);
        }
      }
    }
  }
}

// ---------------- Combine: out[t] = g0*y[slot0(t)] + g1*y[slot1(t)]
__global__ __launch_bounds__(256) void combine_kernel(
    const u16* __restrict__ y, const int* __restrict__ tope,
    const float2* __restrict__ gate2, const int2* __restrict__ pos2,
    const int* __restrict__ counts, float* __restrict__ out) {
  int t = blockIdx.x;
  int pk = tope[t];
  int e0 = pk & 0xff, e1 = (pk >> 8) & 0xff;
  float2 g = gate2[t];
  int2 p = pos2[t];
  int hb0 = prefix_base(counts, e0);
  int hb1 = prefix_base(counts, e1);
  size_t s0 = (size_t)(hb0 + p.x) * H_DIM + threadIdx.x * 4;
  size_t s1 = (size_t)(hb1 + p.y) * H_DIM + threadIdx.x * 4;
  ushort4 a = *(const ushort4*)(y + s0);
  ushort4 b = *(const ushort4*)(y + s1);
  float4 o;
  o.x = g.x * bf2f(a.x) + g.y * bf2f(b.x);
  o.y = g.x * bf2f(a.y) + g.y * bf2f(b.y);
  o.z = g.x * bf2f(a.z) + g.y * bf2f(b.z);
  o.w = g.x * bf2f(a.w) + g.y * bf2f(b.w);
  *(float4*)(out + (size_t)t * H_DIM + threadIdx.x * 4) = o;
}

extern "C" void kernel_launch(void* const* d_in, const int* in_sizes, int n_in,
                              void* d_out, int out_size, void* d_ws, size_t ws_size,
                              hipStream_t stream) {
  const float* x  = (const float*)d_in[0];
  const float* rw = (const float*)d_in[1];
  const float* w1 = (const float*)d_in[2];
  const float* w2 = (const float*)d_in[3];
  float* out = (float*)d_out;

  // ws layout (bytes), total ~151.5 MB. y aliases w1b (dead after g1).
  char* ws = (char*)d_ws;
  u16* xb       = (u16*)(ws);                        // 16,777,216
  u16* w1b      = (u16*)(ws + 16777216);             // 33,554,432
  u16* y        = (u16*)(ws + 16777216);             // alias of w1b
  u16* w2b      = (u16*)(ws + 50331648);             // 33,554,432
  u16* h        = (u16*)(ws + 83886080);             // 67,108,864
  int* tok_list = (int*)(ws + 150994944);            // 262,144
  int* tope     = (int*)(ws + 151257088);            // 32,768
  float2* gate2 = (float2*)(ws + 151289856);         // 65,536
  int2* pos2    = (int2*)(ws + 151355392);           // 65,536
  int* counts   = (int*)(ws + 151420928);            // 32

  prep_kernel<<<T_TOK / 4 + 6144, 256, 0, stream>>>(x, rw, w1, w2, xb, w1b, w2b,
                                                    tope, gate2, counts);
  build_kernel<<<T_TOK / 256, 256, 0, stream>>>(tope, counts, tok_list, pos2);
  // g1: gathered [cnt_e,1024] @ w1[e]^T -> gelu -> h [.,2048]
  moe_gemm<16, 8, H2, true, true>
      <<<NE * 32 * 8, 512, 0, stream>>>(xb, w1b, h, tok_list, counts);
  // g2: h [cnt_e,2048] @ w2[e]^T -> y [.,1024]
  moe_gemm<32, 4, H_DIM, false, false>
      <<<NE * 32 * 4, 512, 0, stream>>>(h, w2b, y, tok_list, counts);
  combine_kernel<<<T_TOK, 256, 0, stream>>>(y, tope, gate2, pos2, counts, out);
}

// Round 3
// 390.718 us; speedup vs baseline: 1.0318x; 1.0318x over previous
//
#include <hip/hip_runtime.h>
#include <stdint.h>
#include <math.h>

// Problem constants (B=4,S=2048 -> T=8192; H=1024; 2H=2048; E=8; K=2)
#define T_TOK 8192
#define H_DIM 1024
#define H2    2048
#define NE    8

typedef unsigned short u16;
typedef __attribute__((ext_vector_type(8))) short bf16x8;   // 8 bf16 in 4 VGPRs
typedef __attribute__((ext_vector_type(4))) float f32x4;    // MFMA 16x16 C/D

__device__ __forceinline__ u16 f32_to_bf16(float f) {
  union { float f; unsigned u; } c; c.f = f;
  unsigned u = c.u + 0x7fffu + ((c.u >> 16) & 1u);  // RNE
  return (u16)(u >> 16);
}
__device__ __forceinline__ float bf2f(u16 v) {
  union { unsigned u; float f; } c; c.u = (unsigned)v << 16; return c.f;
}

// fast gelu (tanh form), |err| vs exact erf-gelu <= ~1e-3 (absmax 1.56e-2
// vs threshold 4.9e-2, stable across rounds)
__device__ __forceinline__ float fast_gelu(float v) {
  float u = v * v;
  float z2 = v * fmaf(u, 0.1029437f, 2.3022078f);
  float e = __builtin_amdgcn_exp2f(z2);
  float r = __builtin_amdgcn_rcpf(1.0f + e);
  return v - v * r;
}

// async global->LDS, 16B per lane. LDS dest is wave-uniform base + lane*16;
// global address is per-lane (exploited for the XOR bank swizzle).
__device__ __forceinline__ void g2l16(const void* g, void* l) {
  __builtin_amdgcn_global_load_lds(
      (const __attribute__((address_space(1))) unsigned*)g,
      (__attribute__((address_space(3))) unsigned*)l, 16, 0, 0);
}

// exclusive prefix of 8 counts, computed per-block
__device__ __forceinline__ int prefix_base(const int* counts, int e) {
  int b = 0;
#pragma unroll
  for (int j = 0; j < NE; j++) b += (j < e) ? counts[j] : 0;
  return b;
}

// ---------------- Prep: router (blocks 0..2047) + w1/w2 cvt (rest).
__global__ __launch_bounds__(256) void prep_kernel(
    const float* __restrict__ x, const float* __restrict__ rw,
    const float* __restrict__ w1, const float* __restrict__ w2,
    u16* __restrict__ xb, u16* __restrict__ w1b, u16* __restrict__ w2b,
    int* __restrict__ tope, float2* __restrict__ gate2,
    int* __restrict__ counts) {
  int blk = blockIdx.x;
  if (blk < T_TOK / 4) {
    int wave = threadIdx.x >> 6;
    int lane = threadIdx.x & 63;
    int t = blk * 4 + wave;
    const float4* x4 = (const float4*)(x + (size_t)t * H_DIM);
    const float4* rw4 = (const float4*)rw;
    u16* xbrow = xb + (size_t)t * H_DIM;

    double acc[NE];
#pragma unroll
    for (int e = 0; e < NE; e++) acc[e] = 0.0;
#pragma unroll
    for (int i = 0; i < 4; i++) {
      int c = lane + 64 * i;
      float4 xv = x4[c];
      ushort4 bv = make_ushort4(f32_to_bf16(xv.x), f32_to_bf16(xv.y),
                                f32_to_bf16(xv.z), f32_to_bf16(xv.w));
      *(ushort4*)(xbrow + c * 4) = bv;
#pragma unroll
      for (int e = 0; e < NE; e++) {
        float4 wv = rw4[e * 256 + c];
        acc[e] += (double)xv.x * wv.x + (double)xv.y * wv.y +
                  (double)xv.z * wv.z + (double)xv.w * wv.w;
      }
    }
#pragma unroll
    for (int off = 32; off >= 1; off >>= 1)
#pragma unroll
      for (int e = 0; e < NE; e++) acc[e] += __shfl_xor(acc[e], off, 64);

    if (lane == 0) {
      int e0 = 0; double v0 = acc[0];
#pragma unroll
      for (int e = 1; e < NE; e++) if (acc[e] > v0) { v0 = acc[e]; e0 = e; }
      int e1 = -1; double v1 = -1e300;
#pragma unroll
      for (int e = 0; e < NE; e++) if (e != e0 && acc[e] > v1) { v1 = acc[e]; e1 = e; }
      double ex = exp(v1 - v0);
      tope[t] = e0 | (e1 << 8);
      gate2[t] = make_float2((float)(1.0 / (1.0 + ex)), (float)(ex / (1.0 + ex)));
    }
  } else {
    int cb = blk - T_TOK / 4;
    if (cb == 0 && threadIdx.x < NE) counts[threadIdx.x] = 0;
    const float* src; u16* dst;
    if (cb < 3072) { src = w1; dst = w1b; }
    else           { src = w2; dst = w2b; cb -= 3072; }
    const int n4 = NE * H2 * H_DIM / 4;
    const int stride = 3072 * 256;
    const float4* s4 = (const float4*)src;
    for (int i = cb * 256 + threadIdx.x; i < n4; i += stride) {
      float4 v = s4[i];
      *(ushort4*)(dst + (size_t)i * 4) = make_ushort4(
          f32_to_bf16(v.x), f32_to_bf16(v.y), f32_to_bf16(v.z), f32_to_bf16(v.w));
    }
  }
}

// ---------------- Build expert lists: counting sort over 8 bins.
__global__ __launch_bounds__(256) void build_kernel(
    const int* __restrict__ tope, int* __restrict__ counts,
    int* __restrict__ tok_list, int2* __restrict__ pos2) {
  __shared__ int cts[4][NE];
  __shared__ int gbase[NE];
  int tid = threadIdx.x, lane = tid & 63, w = tid >> 6;
  int t = blockIdx.x * 256 + tid;
  int pk = tope[t];
  int e0 = pk & 0xff, e1 = (pk >> 8) & 0xff;
  unsigned long long lt = ((unsigned long long)1 << lane) - 1;

  int r0 = 0, r1 = 0;
#pragma unroll
  for (int e = 0; e < NE; e++) {
    unsigned long long b0 = __ballot(e0 == e);
    unsigned long long b1 = __ballot(e1 == e);
    int n0 = __popcll(b0), n1 = __popcll(b1);
    if (e0 == e) r0 = __popcll(b0 & lt);
    if (e1 == e) r1 = n0 + __popcll(b1 & lt);
    if (lane == 0) cts[w][e] = n0 + n1;
  }
  __syncthreads();
  if (tid < NE) {
    int bt = cts[0][tid] + cts[1][tid] + cts[2][tid] + cts[3][tid];
    gbase[tid] = atomicAdd(&counts[tid], bt);
  }
  __syncthreads();
  int off0 = gbase[e0] + r0;
  int off1 = gbase[e1] + r1;
#pragma unroll
  for (int wp = 0; wp < 4; wp++) {
    if (wp < w) { off0 += cts[wp][e0]; off1 += cts[wp][e1]; }
  }
  tok_list[e0 * T_TOK + off0] = t;
  tok_list[e1 * T_TOK + off1] = t;
  pos2[t] = make_int2(off0, off1);
}

// ---------------- Grouped GEMM: minimum-sync double-buffer schedule.
// 256x256 tile, BK=64, 8 waves (2M x 4N, each 128x64 out), LDS 128 KiB =
// [2 tensors][2 dbuf][256][64] bf16.
//
// Per K-tile t (buf d = t&1), exactly ONE barrier + ONE vmcnt:
//   vmcnt(0)            // retires stage(t), issued a full tile ago (~free)
//   s_barrier           // also: all waves done reading buf d^1 (tile t-1)
//   24 ds_read_b128 from buf d, in consumption order
//   stage(t+1) -> buf d^1   (8 x global_load_lds; LDS-write is WAR-safe:
//                            all reads of d^1 retired before the barrier)
//   sched_barrier; setprio(1); 64 MFMA; setprio(0)
// The compiler's counted lgkmcnt lets ~20 reads stay in flight under the
// first MFMAs (read/MFMA overlap R0-R2 never had). No per-phase barriers.
//
// XOR swizzle for 64B rows: phys slot = logical chunk ^ (row&7); staged via
// pre-swizzled GLOBAL chunk, LDS dest linear (both-sides-or-neither).
//
// XCD pinning: hardware assigns consecutive blockIdx round-robin to XCDs,
// so e = blockIdx&7 puts each expert's whole panel (4 MB weights) on one
// XCD's L2. Bijective (grid % 8 == 0). Heuristic only - correctness-safe.
template <int NKT, int NT, int OUTN, bool GATHER, bool GELU>
__global__ __launch_bounds__(512, 2) void moe_gemm(
    const u16* __restrict__ A, const u16* __restrict__ W,
    u16* __restrict__ O, const int* __restrict__ tok_list,
    const int* __restrict__ counts) {
  int e = blockIdx.x & 7;
  int rem = blockIdx.x >> 3;               // 0 .. 32*NT-1
  int mt = rem / NT, nt = rem % NT;
  int cnt = counts[e];
  int m0 = mt * 256;
  if (m0 >= cnt) return;
  int base = prefix_base(counts, e);
  const int K = NKT * 64;

  __shared__ u16 lA[2][16384];   // [dbuf][256][64] bf16 = 64 KB
  __shared__ u16 lB[2][16384];   // 64 KB

  int tid = threadIdx.x;
  int ln = tid & 63, w = tid >> 6;
  int wr = w >> 2, wc = w & 3;             // 2M x 4N wave grid
  int quad = ln >> 4, l16 = ln & 15;

  // ---- staging: call c covers rows c*64..c*64+63; 16B unit u = c*512+tid;
  // phys slot u&7 holds global chunk (u&7)^(row&7).
  const u16* We = W + (size_t)e * OUTN * K;
  const u16* aptr[4]; const u16* bptr[4];
#pragma unroll
  for (int c = 0; c < 4; ++c) {
    int u = c * 512 + tid;
    int row = u >> 3;
    int chunk = (u & 7) ^ (row & 7);
    int ar = m0 + row; if (ar > cnt - 1) ar = cnt - 1;
    const u16* ab;
    if (GATHER) ab = A + (size_t)tok_list[e * T_TOK + ar] * K;
    else        ab = A + (size_t)(base + ar) * K;
    aptr[c] = ab + chunk * 8;
    bptr[c] = We + (size_t)(nt * 256 + row) * K + chunk * 8;
  }

  // ---- read addresses (u16 within one 16384-u16 buffer)
  int adA[8][2], adB[4][2];
#pragma unroll
  for (int f = 0; f < 8; ++f) {
    int r = wr * 128 + f * 16 + l16;
#pragma unroll
    for (int kk = 0; kk < 2; ++kk)
      adA[f][kk] = r * 64 + ((((kk << 2) | quad) ^ (r & 7)) << 3);
  }
#pragma unroll
  for (int j = 0; j < 4; ++j) {
    int r = wc * 64 + j * 16 + l16;
#pragma unroll
    for (int kk = 0; kk < 2; ++kk)
      adB[j][kk] = r * 64 + ((((kk << 2) | quad) ^ (r & 7)) << 3);
  }

  f32x4 acc[8][4];
#pragma unroll
  for (int i = 0; i < 8; i++)
#pragma unroll
    for (int j = 0; j < 4; j++)
#pragma unroll
      for (int r = 0; r < 4; r++) acc[i][j][r] = 0.f;

  // prologue: tile 0 in flight
#pragma unroll
  for (int c = 0; c < 4; ++c) {
    g2l16(aptr[c], &lA[0][(c * 512 + tid) * 8]);
    g2l16(bptr[c], &lB[0][(c * 512 + tid) * 8]);
  }

#pragma unroll 1
  for (int t = 0; t < NKT; ++t) {
    int d = t & 1;
    asm volatile("s_waitcnt vmcnt(0)" ::: "memory");
    __builtin_amdgcn_s_barrier();
    __builtin_amdgcn_sched_barrier(0);

    const u16* Ab = &lA[d][0];
    const u16* Bb = &lB[d][0];
    // reads in consumption order: af[0], all B, af[1..7]
    bf16x8 af[8], af2[8], bf[4], bf2v[4];
    af[0]  = *(const bf16x8*)(Ab + adA[0][0]);
    af2[0] = *(const bf16x8*)(Ab + adA[0][1]);
#pragma unroll
    for (int j = 0; j < 4; ++j) {
      bf[j]   = *(const bf16x8*)(Bb + adB[j][0]);
      bf2v[j] = *(const bf16x8*)(Bb + adB[j][1]);
    }
#pragma unroll
    for (int f = 1; f < 8; ++f) {
      af[f]  = *(const bf16x8*)(Ab + adA[f][0]);
      af2[f] = *(const bf16x8*)(Ab + adA[f][1]);
    }

    if (t + 1 < NKT) {
#pragma unroll
      for (int c = 0; c < 4; ++c) {
        g2l16(aptr[c] + (t + 1) * 64, &lA[d ^ 1][(c * 512 + tid) * 8]);
        g2l16(bptr[c] + (t + 1) * 64, &lB[d ^ 1][(c * 512 + tid) * 8]);
      }
    }
    __builtin_amdgcn_sched_barrier(0);

    __builtin_amdgcn_s_setprio(1);
#pragma unroll
    for (int mi = 0; mi < 8; ++mi) {
#pragma unroll
      for (int ni = 0; ni < 4; ++ni)
        acc[mi][ni] = __builtin_amdgcn_mfma_f32_16x16x32_bf16(
            af[mi], bf[ni], acc[mi][ni], 0, 0, 0);
#pragma unroll
      for (int ni = 0; ni < 4; ++ni)
        acc[mi][ni] = __builtin_amdgcn_mfma_f32_16x16x32_bf16(
            af2[mi], bf2v[ni], acc[mi][ni], 0, 0, 0);
    }
    __builtin_amdgcn_s_setprio(0);
  }

  // epilogue: C/D layout col=lane&15, row=quad*4+reg
#pragma unroll
  for (int mi = 0; mi < 8; ++mi) {
    int rb = wr * 128 + mi * 16 + quad * 4;
#pragma unroll
    for (int r = 0; r < 4; ++r) {
      int grow = m0 + rb + r;
      if (grow < cnt) {
        size_t o = (size_t)(base + grow) * OUTN + nt * 256 + wc * 64 + l16;
#pragma unroll
        for (int ni = 0; ni < 4; ++ni) {
          float v = acc[mi][ni][r];
          if (GELU) v = fast_gelu(v);
          O[o + ni * 16] = f32_to_bf16(v);
        }
      }
    }
  }
}

// ---------------- Combine: out[t] = g0*y[slot0(t)] + g1*y[slot1(t)]
__global__ __launch_bounds__(256) void combine_kernel(
    const u16* __restrict__ y, const int* __restrict__ tope,
    const float2* __restrict__ gate2, const int2* __restrict__ pos2,
    const int* __restrict__ counts, float* __restrict__ out) {
  int t = blockIdx.x;
  int pk = tope[t];
  int e0 = pk & 0xff, e1 = (pk >> 8) & 0xff;
  float2 g = gate2[t];
  int2 p = pos2[t];
  int hb0 = prefix_base(counts, e0);
  int hb1 = prefix_base(counts, e1);
  size_t s0 = (size_t)(hb0 + p.x) * H_DIM + threadIdx.x * 4;
  size_t s1 = (size_t)(hb1 + p.y) * H_DIM + threadIdx.x * 4;
  ushort4 a = *(const ushort4*)(y + s0);
  ushort4 b = *(const ushort4*)(y + s1);
  float4 o;
  o.x = g.x * bf2f(a.x) + g.y * bf2f(b.x);
  o.y = g.x * bf2f(a.y) + g.y * bf2f(b.y);
  o.z = g.x * bf2f(a.z) + g.y * bf2f(b.z);
  o.w = g.x * bf2f(a.w) + g.y * bf2f(b.w);
  *(float4*)(out + (size_t)t * H_DIM + threadIdx.x * 4) = o;
}

extern "C" void kernel_launch(void* const* d_in, const int* in_sizes, int n_in,
                              void* d_out, int out_size, void* d_ws, size_t ws_size,
                              hipStream_t stream) {
  const float* x  = (const float*)d_in[0];
  const float* rw = (const float*)d_in[1];
  const float* w1 = (const float*)d_in[2];
  const float* w2 = (const float*)d_in[3];
  float* out = (float*)d_out;

  // ws layout (bytes), total ~151.5 MB. y aliases w1b (dead after g1).
  char* ws = (char*)d_ws;
  u16* xb       = (u16*)(ws);                        // 16,777,216
  u16* w1b      = (u16*)(ws + 16777216);             // 33,554,432
  u16* y        = (u16*)(ws + 16777216);             // alias of w1b
  u16* w2b      = (u16*)(ws + 50331648);             // 33,554,432
  u16* h        = (u16*)(ws + 83886080);             // 67,108,864
  int* tok_list = (int*)(ws + 150994944);            // 262,144
  int* tope     = (int*)(ws + 151257088);            // 32,768
  float2* gate2 = (float2*)(ws + 151289856);         // 65,536
  int2* pos2    = (int2*)(ws + 151355392);           // 65,536
  int* counts   = (int*)(ws + 151420928);            // 32

  prep_kernel<<<T_TOK / 4 + 6144, 256, 0, stream>>>(x, rw, w1, w2, xb, w1b, w2b,
                                                    tope, gate2, counts);
  build_kernel<<<T_TOK / 256, 256, 0, stream>>>(tope, counts, tok_list, pos2);
  // g1: gathered [cnt_e,1024] @ w1[e]^T -> gelu -> h [.,2048]
  moe_gemm<16, 8, H2, true, true>
      <<<NE * 32 * 8, 512, 0, stream>>>(xb, w1b, h, tok_list, counts);
  // g2: h [cnt_e,2048] @ w2[e]^T -> y [.,1024]
  moe_gemm<32, 4, H_DIM, false, false>
      <<<NE * 32 * 4, 512, 0, stream>>>(h, w2b, y, tok_list, counts);
  combine_kernel<<<T_TOK, 256, 0, stream>>>(y, tope, gate2, pos2, counts, out);
}